// Round 1
// baseline (1450.584 us; speedup 1.0000x reference)
//
#include <hip/hip_runtime.h>
#include <hip/hip_bf16.h>

#define T_TOK 2048
#define HDIM  2048
#define NEXP  8
#define IDIM  4096
#define ROWCAP 5120
#define MAXTILES 40

typedef __attribute__((ext_vector_type(8))) short short8;
typedef __attribute__((ext_vector_type(4))) float f32x4;

__device__ __forceinline__ unsigned int f2bf1(float x){
  __hip_bfloat16 h = __float2bfloat16(x);
  unsigned short r; __builtin_memcpy(&r, &h, 2); return (unsigned int)r;
}
__device__ __forceinline__ unsigned int pk2(float a, float b){
  return f2bf1(a) | (f2bf1(b) << 16);
}

#define GLL16(g, s) __builtin_amdgcn_global_load_lds( \
    (const __attribute__((address_space(1))) void*)(g), \
    (__attribute__((address_space(3))) void*)(s), 16, 0, 0)

// ---------------- K0: X fp32 -> bf16 ----------------
__global__ __launch_bounds__(256) void k_cvt(const float* __restrict__ X, uint4* __restrict__ Xb4){
  const int g = blockIdx.x*256 + threadIdx.x;            // 524288 threads, 8 floats each
  const float4* X4 = (const float4*)X;
  float4 x0 = X4[(long)g*2], x1 = X4[(long)g*2+1];
  uint4 p;
  p.x = pk2(x0.x,x0.y); p.y = pk2(x0.z,x0.w);
  p.z = pk2(x1.x,x1.y); p.w = pk2(x1.z,x1.w);
  Xb4[g] = p;
}

// ---------------- K1: router (fp32 exact) ----------------
__global__ __launch_bounds__(256) void k_router(const float* __restrict__ X, const float* __restrict__ GW,
                                                int* __restrict__ te2, float* __restrict__ tw2){
  const int t = blockIdx.x*4 + (threadIdx.x>>6);
  const int l = threadIdx.x & 63;
  const float* x = X + (long)t*HDIM;
  float acc[NEXP];
  #pragma unroll
  for (int e=0;e<NEXP;e++) acc[e]=0.f;
  for (int h=l; h<HDIM; h+=64){
    const float xv = x[h];
    #pragma unroll
    for (int e=0;e<NEXP;e++) acc[e] += xv * GW[e*HDIM + h];
  }
  #pragma unroll
  for (int e=0;e<NEXP;e++){
    #pragma unroll
    for (int off=32; off; off>>=1) acc[e] += __shfl_xor(acc[e], off);
  }
  if (l==0){
    int e0=0; float l0=acc[0];
    #pragma unroll
    for (int e=1;e<NEXP;e++) if (acc[e]>l0){ l0=acc[e]; e0=e; }
    int e1=-1; float l1=-1e30f;
    #pragma unroll
    for (int e=0;e<NEXP;e++) if (e!=e0 && acc[e]>l1){ l1=acc[e]; e1=e; }
    const float w0 = 1.f/(1.f + expf(l1 - l0));
    te2[2*t]=e0; te2[2*t+1]=e1;
    tw2[2*t]=w0; tw2[2*t+1]=1.f-w0;
  }
}

// ---------------- K2: build compact per-expert row lists + tile table ----------------
__global__ __launch_bounds__(256) void k_build(const int* __restrict__ te2, const float* __restrict__ tw2,
                                               int* __restrict__ meta, int* __restrict__ rowinfo,
                                               float* __restrict__ roww){
  __shared__ int cnt[NEXP], cur[NEXP], poffs[NEXP];
  const int tid = threadIdx.x;
  if (tid<NEXP){ cnt[tid]=0; cur[tid]=0; }
  __syncthreads();
  for (int i=tid; i<2*T_TOK; i+=256) atomicAdd(&cnt[te2[i]], 1);
  __syncthreads();
  if (tid==0){
    int p=0, nt=0;
    for (int e=0;e<NEXP;e++){
      poffs[e]=p;
      const int n = cnt[e];
      const int ntile = (n+127)>>7;
      for (int j=0;j<ntile;j++){
        meta[16+nt*4+0]=e;
        meta[16+nt*4+1]=p+j*128;
        meta[16+nt*4+2]=(n-j*128 < 128) ? (n-j*128) : 128;
        nt++;
      }
      p += ntile*128;
    }
    meta[0]=nt;
  }
  __syncthreads();
  for (int i=tid;i<ROWCAP;i+=256){ rowinfo[i]=0; roww[i]=0.f; }
  __syncthreads();
  for (int i=tid;i<2*T_TOK;i+=256){
    const int e = te2[i];
    const int p = atomicAdd(&cur[e],1);
    const int idx = poffs[e]+p;
    rowinfo[idx]=i;            // i = token*2 + slot
    roww[idx]=tw2[i];
  }
}

// ---------------- K3: grouped GEMM1 + fused SwiGLU ----------------
// out h[row][ct*64 + 0..63] = silu(X@w13_gate^T) * (X@w13_up^T)
__global__ __launch_bounds__(256) void k_gemm1(const unsigned short* __restrict__ Xb,
      const float* __restrict__ W13, const int* __restrict__ meta,
      const int* __restrict__ rowinfo, unsigned short* __restrict__ Hb){
  __shared__ uint4 sA[1024];   // 2 bufs x [k16*128 + row]
  __shared__ uint4 sB[1024];   // 2 bufs x [strip*256 + k16*64 + col]  strip0=gate strip1=up
  const int rt = blockIdx.x, ct = blockIdx.y;
  if (rt >= meta[0]) return;
  const int e = meta[16+rt*4+0], rbase = meta[16+rt*4+1];
  const int tid = threadIdx.x, w = tid>>6, l = tid&63;
  const int wr = w & 1, wc = w >> 1;

  // A gather sources (2 slots of 16B per thread)
  const int row0 = tid & 127, k0 = tid >> 7;
  const int row1 = (256+tid) & 127, k1 = (256+tid) >> 7;
  const unsigned short* a0 = Xb + (long)(rowinfo[rbase+row0]>>1)*HDIM + k0*8;
  const unsigned short* a1 = Xb + (long)(rowinfo[rbase+row1]>>1)*HDIM + k1*8;

  // B sources: gate rows ct*64.., up rows IDIM+ct*64.. ; 2 fp32-quads each
  const long ebase = (long)e * (2*IDIM) * HDIM;
  const int br0 = tid>>3, bk = tid&7;          // br0 in [0,32)
  const int br1 = br0 + 32;
  const float* g0 = W13 + ebase + (long)(ct*64+br0)*HDIM + bk*4;
  const float* g1 = W13 + ebase + (long)(ct*64+br1)*HDIM + bk*4;
  const float* u0 = g0 + (long)IDIM*HDIM;
  const float* u1 = g1 + (long)IDIM*HDIM;

  const f32x4 fz = {0.f,0.f,0.f,0.f};
  f32x4 accG[4][2], accU[4][2];
  #pragma unroll
  for (int m=0;m<4;m++){
    #pragma unroll
    for (int n=0;n<2;n++){ accG[m][n]=fz; accU[m][n]=fz; }
  }

#define STORE_B1(nb, vg, vu, br) do{ \
  ((uint2*)&sB[(nb)*512 + (bk>>1)*64 + (br)])[bk&1] = make_uint2(pk2((vg).x,(vg).y), pk2((vg).z,(vg).w)); \
  ((uint2*)&sB[(nb)*512 + 256 + (bk>>1)*64 + (br)])[bk&1] = make_uint2(pk2((vu).x,(vu).y), pk2((vu).z,(vu).w)); \
}while(0)

  const int NT = HDIM/32;   // 64 K-steps
  int curb = 0;
  // prologue into buf 0
  GLL16(a0, &sA[w<<6]);
  GLL16(a1, &sA[256+(w<<6)]);
  {
    float4 vg0=*(const float4*)g0, vg1=*(const float4*)g1;
    float4 vu0=*(const float4*)u0, vu1=*(const float4*)u1;
    STORE_B1(0, vg0, vu0, br0);
    STORE_B1(0, vg1, vu1, br1);
  }
  __syncthreads();

  const int kg = l>>4, ln = l&15;
  for (int kt=0; kt<NT; kt++){
    const int nb = curb^1;
    const bool pf = (kt+1 < NT);
    float4 vg0, vg1, vu0, vu1;
    if (pf){
      const int ko = (kt+1)*32;
      GLL16(a0+ko, &sA[nb*512 + (w<<6)]);
      GLL16(a1+ko, &sA[nb*512 + 256 + (w<<6)]);
      vg0 = *(const float4*)(g0+ko); vg1 = *(const float4*)(g1+ko);
      vu0 = *(const float4*)(u0+ko); vu1 = *(const float4*)(u1+ko);
    }
    short8 af[4];
    #pragma unroll
    for (int m=0;m<4;m++) af[m] = *(const short8*)&sA[curb*512 + kg*128 + wr*64 + m*16 + ln];
    short8 bg[2], bu[2];
    #pragma unroll
    for (int n=0;n<2;n++){
      bg[n] = *(const short8*)&sB[curb*512 + kg*64 + wc*32 + n*16 + ln];
      bu[n] = *(const short8*)&sB[curb*512 + 256 + kg*64 + wc*32 + n*16 + ln];
    }
    #pragma unroll
    for (int m=0;m<4;m++){
      #pragma unroll
      for (int n=0;n<2;n++){
        accG[m][n] = __builtin_amdgcn_mfma_f32_16x16x32_bf16(af[m], bg[n], accG[m][n], 0,0,0);
        accU[m][n] = __builtin_amdgcn_mfma_f32_16x16x32_bf16(af[m], bu[n], accU[m][n], 0,0,0);
      }
    }
    if (pf){
      STORE_B1(nb, vg0, vu0, br0);
      STORE_B1(nb, vg1, vu1, br1);
    }
    __syncthreads();
    curb = nb;
  }
  // epilogue: SwiGLU, store all 128 rows (padding rows harmless)
  #pragma unroll
  for (int m=0;m<4;m++){
    #pragma unroll
    for (int n=0;n<2;n++){
      #pragma unroll
      for (int r=0;r<4;r++){
        const int rloc = wr*64 + m*16 + kg*4 + r;
        const float gv = accG[m][n][r], uv = accU[m][n][r];
        const float hv = gv / (1.f + expf(-gv)) * uv;
        const int col = (ct<<6) + wc*32 + n*16 + ln;
        Hb[(long)(rbase+rloc)*IDIM + col] = (unsigned short)f2bf1(hv);
      }
    }
  }
#undef STORE_B1
}

// ---------------- K4: grouped GEMM2, scaled scatter to (token,slot) rows ----------------
__global__ __launch_bounds__(256) void k_gemm2(const unsigned short* __restrict__ Hb,
      const float* __restrict__ W2, const int* __restrict__ meta,
      const int* __restrict__ rowinfo, const float* __restrict__ roww,
      float* __restrict__ slotout){
  __shared__ uint4 sA[1024];  // 2 x [k16*128 + row]
  __shared__ uint4 sB[1024];  // 2 x [k16*128 + col]
  const int rt = blockIdx.x, ct = blockIdx.y;
  if (rt >= meta[0]) return;
  const int e = meta[16+rt*4+0], rbase = meta[16+rt*4+1], nloc = meta[16+rt*4+2];
  const int tid = threadIdx.x, w = tid>>6, l = tid&63;
  const int wr = w>>1, wc = w&1;

  const int row0 = tid&127, k0 = tid>>7;
  const int row1 = (256+tid)&127, k1 = (256+tid)>>7;
  const unsigned short* a0 = Hb + (long)(rbase+row0)*IDIM + k0*8;
  const unsigned short* a1 = Hb + (long)(rbase+row1)*IDIM + k1*8;

  const long ebase = (long)e*HDIM*IDIM;
  const int brr = tid>>3, bk = tid&7;        // brr in [0,32), rows advance 32 per j
  const float* b0 = W2 + ebase + (long)((ct<<7) + brr)*IDIM + bk*4;

  const f32x4 fz = {0.f,0.f,0.f,0.f};
  f32x4 acc[4][4];
  #pragma unroll
  for (int m=0;m<4;m++){
    #pragma unroll
    for (int n=0;n<4;n++) acc[m][n]=fz;
  }

#define STORE_B2(nb, v, row) \
  ((uint2*)&sB[(nb)*512 + (bk>>1)*128 + (row)])[bk&1] = make_uint2(pk2((v).x,(v).y), pk2((v).z,(v).w))

  const int NT = IDIM/32;   // 128 K-steps
  int curb = 0;
  GLL16(a0, &sA[w<<6]);
  GLL16(a1, &sA[256+(w<<6)]);
  {
    #pragma unroll
    for (int j=0;j<4;j++){
      float4 v = *(const float4*)(b0 + (long)j*32*IDIM);
      STORE_B2(0, v, brr + j*32);
    }
  }
  __syncthreads();

  const int kg = l>>4, ln = l&15;
  for (int kt=0; kt<NT; kt++){
    const int nb = curb^1;
    const bool pf = (kt+1 < NT);
    float4 vb[4];
    if (pf){
      const int ko = (kt+1)*32;
      GLL16(a0+ko, &sA[nb*512 + (w<<6)]);
      GLL16(a1+ko, &sA[nb*512 + 256 + (w<<6)]);
      #pragma unroll
      for (int j=0;j<4;j++) vb[j] = *(const float4*)(b0 + ko + (long)j*32*IDIM);
    }
    short8 af[4], bfm[4];
    #pragma unroll
    for (int m=0;m<4;m++) af[m] = *(const short8*)&sA[curb*512 + kg*128 + wr*64 + m*16 + ln];
    #pragma unroll
    for (int n=0;n<4;n++) bfm[n] = *(const short8*)&sB[curb*512 + kg*128 + wc*64 + n*16 + ln];
    #pragma unroll
    for (int m=0;m<4;m++){
      #pragma unroll
      for (int n=0;n<4;n++)
        acc[m][n] = __builtin_amdgcn_mfma_f32_16x16x32_bf16(af[m], bfm[n], acc[m][n], 0,0,0);
    }
    if (pf){
      #pragma unroll
      for (int j=0;j<4;j++) STORE_B2(nb, vb[j], brr + j*32);
    }
    __syncthreads();
    curb = nb;
  }
  // epilogue: scale by routing weight, scatter to slot rows, mask padding
  #pragma unroll
  for (int m=0;m<4;m++){
    const int rl0 = wr*64 + m*16 + kg*4;
    #pragma unroll
    for (int r=0;r<4;r++){
      const int rloc = rl0 + r;
      if (rloc < nloc){
        const int info = rowinfo[rbase + rloc];
        const float wt = roww[rbase + rloc];
        #pragma unroll
        for (int n=0;n<4;n++){
          const int col = (ct<<7) + wc*64 + n*16 + ln;
          slotout[(long)info*HDIM + col] = wt * acc[m][n][r];
        }
      }
    }
  }
#undef STORE_B2
}

// ---------------- K5: combine the two slots per token ----------------
__global__ __launch_bounds__(256) void k_combine(const float4* __restrict__ slot4, float4* __restrict__ out4){
  const long g = (long)blockIdx.x*256 + threadIdx.x;    // T*H/4 = 1048576 chunks
  const long t = g >> 9;                                // 512 float4 per row
  const long c = g & 511;
  float4 x = slot4[(t*2)*512 + c];
  float4 y = slot4[(t*2+1)*512 + c];
  out4[g] = make_float4(x.x+y.x, x.y+y.y, x.z+y.z, x.w+y.w);
}

extern "C" void kernel_launch(void* const* d_in, const int* in_sizes, int n_in,
                              void* d_out, int out_size, void* d_ws, size_t ws_size,
                              hipStream_t stream) {
  const float* X   = (const float*)d_in[0];
  const float* GW  = (const float*)d_in[1];
  const float* W13 = (const float*)d_in[2];
  const float* W2  = (const float*)d_in[3];
  // d_in[4] = top_k (always 2 here)

  char* ws = (char*)d_ws;
  unsigned short* Xb   = (unsigned short*)(ws);                  // 8 MB
  unsigned short* Hb   = (unsigned short*)(ws + 8388608);        // 40 MB
  float*          slot = (float*)(ws + 50331648);                // 32 MB
  int*            te2  = (int*)(ws + 83886080);
  float*          tw2  = (float*)(ws + 83902464);
  int*            rowinfo = (int*)(ws + 83918848);
  float*          roww = (float*)(ws + 83939328);
  int*            meta = (int*)(ws + 83959808);

  hipLaunchKernelGGL(k_cvt,    dim3(2048), dim3(256), 0, stream, X, (uint4*)Xb);
  hipLaunchKernelGGL(k_router, dim3(512),  dim3(256), 0, stream, X, GW, te2, tw2);
  hipLaunchKernelGGL(k_build,  dim3(1),    dim3(256), 0, stream, te2, tw2, meta, rowinfo, roww);
  hipLaunchKernelGGL(k_gemm1,  dim3(MAXTILES, IDIM/64),  dim3(256), 0, stream, Xb, W13, meta, rowinfo, Hb);
  hipLaunchKernelGGL(k_gemm2,  dim3(MAXTILES, HDIM/128), dim3(256), 0, stream, Hb, W2, meta, rowinfo, roww, slot);
  hipLaunchKernelGGL(k_combine,dim3(4096), dim3(256), 0, stream, (const float4*)slot, (float4*)d_out);
}